// Round 1
// baseline (420.453 us; speedup 1.0000x reference)
//
#include <hip/hip_runtime.h>

#define TWO_PI 6.283185307179586f

typedef _Float16 half8 __attribute__((ext_vector_type(8)));
typedef float floatx4 __attribute__((ext_vector_type(4)));

// ------------------------------------------------------------------
// Stage A: per-proposal AABB (min/max over 8 corners), volume, sem mask
// ------------------------------------------------------------------
__global__ void prep_prop(const float* __restrict__ logits,
                          const float* __restrict__ corners,
                          float* __restrict__ mn, float* __restrict__ mx,
                          float* __restrict__ vol, float* __restrict__ msk)
{
    int idx = blockIdx.x * 256 + threadIdx.x;      // 8192 = 32*256
    const float* c = corners + (size_t)idx * 24;
    float mn0 = c[0], mn1 = c[1], mn2 = c[2];
    float mx0 = mn0, mx1 = mn1, mx2 = mn2;
#pragma unroll
    for (int k = 1; k < 8; k++) {
        float v0 = c[k*3+0], v1 = c[k*3+1], v2 = c[k*3+2];
        mn0 = fminf(mn0, v0); mx0 = fmaxf(mx0, v0);
        mn1 = fminf(mn1, v1); mx1 = fmaxf(mx1, v1);
        mn2 = fminf(mn2, v2); mx2 = fmaxf(mx2, v2);
    }
    mn[idx*3+0] = mn0; mn[idx*3+1] = mn1; mn[idx*3+2] = mn2;
    mx[idx*3+0] = mx0; mx[idx*3+1] = mx1; mx[idx*3+2] = mx2;
    vol[idx] = (mx0-mn0)*(mx1-mn1)*(mx2-mn2);
    const float* lg = logits + (size_t)idx * 19;
    float bv = lg[0]; int bi = 0;
#pragma unroll
    for (int k = 1; k < 19; k++) { float v = lg[k]; if (v > bv) { bv = v; bi = k; } }
    msk[idx] = (bi != 18) ? 1.0f : 0.0f;
}

// ------------------------------------------------------------------
// Stage B: box query -> IoU argmax over 256 proposals (first-max tiebreak)
// ------------------------------------------------------------------
__global__ void box_match(const float* __restrict__ box_query,
                          const float* __restrict__ mn_p, const float* __restrict__ mx_p,
                          const float* __restrict__ vol_p, const float* __restrict__ msk,
                          int* __restrict__ match_idx)
{
    int gq = blockIdx.x * 256 + threadIdx.x;   // 2048 = 8*256
    int b = gq >> 6;
    const float* cq = box_query + (size_t)gq * 24;
    float mn0 = cq[0], mn1 = cq[1], mn2 = cq[2];
    float mx0 = mn0, mx1 = mn1, mx2 = mn2;
#pragma unroll
    for (int k = 1; k < 8; k++) {
        float v0 = cq[k*3+0], v1 = cq[k*3+1], v2 = cq[k*3+2];
        mn0 = fminf(mn0, v0); mx0 = fmaxf(mx0, v0);
        mn1 = fminf(mn1, v1); mx1 = fmaxf(mx1, v1);
        mn2 = fminf(mn2, v2); mx2 = fmaxf(mx2, v2);
    }
    float volq = (mx0-mn0)*(mx1-mn1)*(mx2-mn2);
    const float* mnb = mn_p + (size_t)b * 256 * 3;
    const float* mxb = mx_p + (size_t)b * 256 * 3;
    const float* vb  = vol_p + (size_t)b * 256;
    const float* mb  = msk + (size_t)b * 256;
    float best = -1.0f; int bi = 0;
    for (int p = 0; p < 256; p++) {
        float e0 = fminf(mx0, mxb[p*3+0]) - fmaxf(mn0, mnb[p*3+0]); e0 = fmaxf(e0, 0.0f);
        float e1 = fminf(mx1, mxb[p*3+1]) - fmaxf(mn1, mnb[p*3+1]); e1 = fmaxf(e1, 0.0f);
        float e2 = fminf(mx2, mxb[p*3+2]) - fmaxf(mn2, mnb[p*3+2]); e2 = fmaxf(e2, 0.0f);
        float inter = (e0*e1)*e2;
        float iou = inter / (volq + vb[p] - inter + 1e-8f) * mb[p];
        if (iou > best) { best = iou; bi = p; }   // strict > keeps first occurrence
    }
    match_idx[gq] = bi;
}

// ------------------------------------------------------------------
// Stage C: click nearest neighbor (argmin of squared dist, first-min tiebreak)
// one wave per click; lane scans stride-64
// ------------------------------------------------------------------
__global__ void click_nn(const float* __restrict__ click_query,
                         const float* __restrict__ enc_xyz,
                         int* __restrict__ nn_ids)
{
    int gq = blockIdx.x * 4 + (threadIdx.x >> 6);   // 2048 waves total
    int lane = threadIdx.x & 63;
    int b = gq >> 6;
    float cx = click_query[gq*3+0];
    float cy = click_query[gq*3+1];
    float cz = click_query[gq*3+2];
    const float* ex = enc_xyz + (size_t)b * 4096 * 3;
    float best = 3.4e38f; int bidx = 0;
    for (int p = lane; p < 4096; p += 64) {
        float dx = cx - ex[p*3+0];
        float dy = cy - ex[p*3+1];
        float dz = cz - ex[p*3+2];
        float d = dx*dx + dy*dy;
        d = d + dz*dz;
        if (d < best) { best = d; bidx = p; }   // ascending p -> first-min per lane
    }
#pragma unroll
    for (int off = 32; off; off >>= 1) {
        float ov = __shfl_down(best, off);
        int   oi = __shfl_down(bidx, off);
        if (ov < best || (ov == best && oi < bidx)) { best = ov; bidx = oi; }
    }
    if (lane == 0) nn_ids[gq] = bidx;
}

// ------------------------------------------------------------------
// Stage D: fourier positional embedding -> click_in[:, 256:512] (f16)
// ------------------------------------------------------------------
__global__ void pos_embed(const float* __restrict__ cq,
                          const float* __restrict__ pc_min,
                          const float* __restrict__ pc_max,
                          const float* __restrict__ gB,
                          _Float16* __restrict__ click_in)
{
    int row = blockIdx.x;        // 2048
    int j = threadIdx.x;         // 128
    int b = row >> 6;
    float m0 = pc_min[b*3+0], m1 = pc_min[b*3+1], m2 = pc_min[b*3+2];
    float tx = (cq[row*3+0] - m0) / (pc_max[b*3+0] - m0) * TWO_PI;
    float ty = (cq[row*3+1] - m1) / (pc_max[b*3+1] - m1) * TWO_PI;
    float tz = (cq[row*3+2] - m2) / (pc_max[b*3+2] - m2) * TWO_PI;
    float p = tx * gB[j] + ty * gB[128+j] + tz * gB[256+j];
    click_in[(size_t)row*512 + 256 + j] = (_Float16)sinf(p);
    click_in[(size_t)row*512 + 384 + j] = (_Float16)cosf(p);
}

// ------------------------------------------------------------------
// Stage E: gather matched features into f16 GEMM inputs
// ------------------------------------------------------------------
__global__ void gather_feats(const float* __restrict__ prop_features,
                             const float* __restrict__ enc_features,
                             const int* __restrict__ match_idx,
                             const int* __restrict__ nn_ids,
                             _Float16* __restrict__ box_in,
                             _Float16* __restrict__ click_in)
{
    int row = blockIdx.x;     // 2048
    int c = threadIdx.x;      // 256
    int b = row >> 6;
    box_in[(size_t)row*256 + c] =
        (_Float16)prop_features[((size_t)b*256 + match_idx[row])*256 + c];
    click_in[(size_t)row*512 + c] =
        (_Float16)enc_features[((size_t)b*4096 + nn_ids[row])*256 + c];
}

// ------------------------------------------------------------------
// Weight transpose+convert: src fp32 [K][N] -> dst f16 [N][K]
// ------------------------------------------------------------------
__global__ void transpose_cvt(const float* __restrict__ src,
                              _Float16* __restrict__ dst, int K, int N)
{
    __shared__ float tile[32][33];
    int n0 = blockIdx.x * 32, k0 = blockIdx.y * 32;
    int tx = threadIdx.x, ty = threadIdx.y;   // 32 x 8
#pragma unroll
    for (int i = 0; i < 32; i += 8)
        tile[ty+i][tx] = src[(size_t)(k0+ty+i)*N + n0+tx];
    __syncthreads();
#pragma unroll
    for (int i = 0; i < 32; i += 8)
        dst[(size_t)(n0+ty+i)*K + k0+tx] = (_Float16)tile[tx][ty+i];
}

// ------------------------------------------------------------------
// f16 MFMA GEMM: C[M,N] = A[M,K] @ Bt[N,K]^T + bias
// 128x128 tile, BK=32, 4 waves each 64x64 (4x4 of 16x16x32 mfma)
// mode 0: relu -> f16 Hout (row-major M*N)
// mode 1: fp32 -> Fout with prompt reshape: off = (m>>6)*786432 + brOff + (m&63)*6144 + n
// ------------------------------------------------------------------
__global__ __launch_bounds__(256) void gemm_bt(
    const _Float16* __restrict__ A,
    const _Float16* __restrict__ Bt,
    const float* __restrict__ bias,
    int M, int N, int K,
    _Float16* __restrict__ Hout,
    float* __restrict__ Fout,
    int mode, long brOff)
{
    __shared__ _Float16 As[128*32];
    __shared__ _Float16 Bs[128*32];
    const int tid = threadIdx.x;
    const int wave = tid >> 6, lane = tid & 63;
    const int bm = blockIdx.x, bn = blockIdx.y;
    const int waveM = (wave & 1) * 64, waveN = (wave >> 1) * 64;
    const int sr = tid >> 2;          // staging row 0..63
    const int sk = (tid & 3) * 8;     // staging k offset {0,8,16,24}
    const int nrow = lane & 15, kgrp = (lane >> 4) * 8;

    floatx4 acc[4][4];
#pragma unroll
    for (int i = 0; i < 4; i++)
#pragma unroll
        for (int j = 0; j < 4; j++) { floatx4 z = {0.f,0.f,0.f,0.f}; acc[i][j] = z; }

    const _Float16* Ar0 = A  + (size_t)(bm*128 + sr) * K + sk;
    const _Float16* Ar1 = Ar0 + (size_t)64 * K;
    const _Float16* Br0 = Bt + (size_t)(bn*128 + sr) * K + sk;
    const _Float16* Br1 = Br0 + (size_t)64 * K;

    for (int kk = 0; kk < K; kk += 32) {
        uint4 a0 = *(const uint4*)(Ar0 + kk);
        uint4 a1 = *(const uint4*)(Ar1 + kk);
        uint4 b0 = *(const uint4*)(Br0 + kk);
        uint4 b1 = *(const uint4*)(Br1 + kk);
        __syncthreads();
        *(uint4*)(As + sr*32 + sk)      = a0;
        *(uint4*)(As + (sr+64)*32 + sk) = a1;
        *(uint4*)(Bs + sr*32 + sk)      = b0;
        *(uint4*)(Bs + (sr+64)*32 + sk) = b1;
        __syncthreads();
        half8 af[4], bf[4];
#pragma unroll
        for (int i = 0; i < 4; i++)
            af[i] = *(const half8*)(As + (waveM + i*16 + nrow)*32 + kgrp);
#pragma unroll
        for (int j = 0; j < 4; j++)
            bf[j] = *(const half8*)(Bs + (waveN + j*16 + nrow)*32 + kgrp);
#pragma unroll
        for (int i = 0; i < 4; i++)
#pragma unroll
            for (int j = 0; j < 4; j++)
                acc[i][j] = __builtin_amdgcn_mfma_f32_16x16x32_f16(af[i], bf[j], acc[i][j], 0, 0, 0);
    }

    // epilogue: C/D layout col = lane&15, row = (lane>>4)*4 + reg
#pragma unroll
    for (int i = 0; i < 4; i++) {
#pragma unroll
        for (int j = 0; j < 4; j++) {
            int col = bn*128 + waveN + j*16 + nrow;
            float bv = bias[col];
#pragma unroll
            for (int r = 0; r < 4; r++) {
                int row = bm*128 + waveM + i*16 + (lane >> 4)*4 + r;
                float v = acc[i][j][r] + bv;
                if (mode == 0) {
                    v = v > 0.f ? v : 0.f;
                    Hout[(size_t)row * N + col] = (_Float16)v;
                } else {
                    size_t off = (size_t)(row >> 6) * 786432 + (size_t)brOff
                               + (size_t)(row & 63) * 6144 + col;
                    Fout[off] = v;
                }
            }
        }
    }
}

// ------------------------------------------------------------------
// prompt_mask: repeat qmasks VQ=8 times, concat box|click
// ------------------------------------------------------------------
__global__ void write_mask(const float* __restrict__ box_qmask,
                           const float* __restrict__ click_qmask,
                           float* __restrict__ out)
{
    int idx = blockIdx.x * 256 + threadIdx.x;   // 32768
    int b = idx >> 10, i = idx & 1023;
    float v = (i < 512) ? box_qmask[b*64 + (i >> 3)]
                        : click_qmask[b*64 + ((i - 512) >> 3)];
    out[25165824 + idx] = v;
}

// ------------------------------------------------------------------
extern "C" void kernel_launch(void* const* d_in, const int* in_sizes, int n_in,
                              void* d_out, int out_size, void* d_ws, size_t ws_size,
                              hipStream_t stream)
{
    const float* sem   = (const float*)d_in[0];
    const float* propf = (const float*)d_in[1];
    const float* boxc  = (const float*)d_in[2];
    const float* encx  = (const float*)d_in[3];
    const float* encf  = (const float*)d_in[4];
    const float* pcmin = (const float*)d_in[5];
    const float* pcmax = (const float*)d_in[6];
    const float* boxq  = (const float*)d_in[7];
    const float* boxm  = (const float*)d_in[8];
    const float* clkq  = (const float*)d_in[9];
    const float* clkm  = (const float*)d_in[10];
    const float* gB    = (const float*)d_in[11];
    const float* bw1   = (const float*)d_in[12];
    const float* bb1   = (const float*)d_in[13];
    const float* bw2   = (const float*)d_in[14];
    const float* bb2   = (const float*)d_in[15];
    const float* cw1   = (const float*)d_in[16];
    const float* cb1   = (const float*)d_in[17];
    const float* cw2   = (const float*)d_in[18];
    const float* cb2   = (const float*)d_in[19];
    float* out = (float*)d_out;
    char* ws = (char*)d_ws;

    float* p_mn  = (float*)(ws + 0);
    float* p_mx  = (float*)(ws + 98304);
    float* p_vol = (float*)(ws + 196608);
    float* p_msk = (float*)(ws + 229376);
    int* midx    = (int*)(ws + 262144);
    int* nnids   = (int*)(ws + 270336);
    _Float16* box_in   = (_Float16*)(ws + 278528);    // 2048x256
    _Float16* click_in = (_Float16*)(ws + 1327104);   // 2048x512
    _Float16* h_box    = (_Float16*)(ws + 3424256);   // 2048x768
    _Float16* h_click  = (_Float16*)(ws + 6569984);   // 2048x768
    _Float16* w1t_box  = (_Float16*)(ws + 9715712);   // 768x256
    _Float16* w2t_box  = (_Float16*)(ws + 10108928);  // 6144x768
    _Float16* w1t_clk  = (_Float16*)(ws + 19546112);  // 768x512
    _Float16* w2t_clk  = (_Float16*)(ws + 20332544);  // 6144x768  (end ~29.7 MB)

    prep_prop<<<32, 256, 0, stream>>>(sem, boxc, p_mn, p_mx, p_vol, p_msk);
    box_match<<<8, 256, 0, stream>>>(boxq, p_mn, p_mx, p_vol, p_msk, midx);
    click_nn<<<512, 256, 0, stream>>>(clkq, encx, nnids);
    pos_embed<<<2048, 128, 0, stream>>>(clkq, pcmin, pcmax, gB, click_in);
    gather_feats<<<2048, 256, 0, stream>>>(propf, encf, midx, nnids, box_in, click_in);

    transpose_cvt<<<dim3(24, 8),   dim3(32, 8), 0, stream>>>(bw1, w1t_box, 256, 768);
    transpose_cvt<<<dim3(192, 24), dim3(32, 8), 0, stream>>>(bw2, w2t_box, 768, 6144);
    transpose_cvt<<<dim3(24, 16),  dim3(32, 8), 0, stream>>>(cw1, w1t_clk, 512, 768);
    transpose_cvt<<<dim3(192, 24), dim3(32, 8), 0, stream>>>(cw2, w2t_clk, 768, 6144);

    gemm_bt<<<dim3(16, 6),  256, 0, stream>>>(box_in, w1t_box, bb1, 2048, 768, 256,
                                              h_box, nullptr, 0, 0);
    gemm_bt<<<dim3(16, 48), 256, 0, stream>>>(h_box, w2t_box, bb2, 2048, 6144, 768,
                                              nullptr, out, 1, 0);
    gemm_bt<<<dim3(16, 6),  256, 0, stream>>>(click_in, w1t_clk, cb1, 2048, 768, 512,
                                              h_click, nullptr, 0, 0);
    gemm_bt<<<dim3(16, 48), 256, 0, stream>>>(h_click, w2t_clk, cb2, 2048, 6144, 768,
                                              nullptr, out, 1, 393216);

    write_mask<<<128, 256, 0, stream>>>(boxm, clkm, out);
}

// Round 2
// 391.417 us; speedup vs baseline: 1.0742x; 1.0742x over previous
//
#include <hip/hip_runtime.h>

#define TWO_PI 6.283185307179586f

typedef _Float16 half8 __attribute__((ext_vector_type(8)));
typedef _Float16 half4 __attribute__((ext_vector_type(4)));
typedef float floatx4 __attribute__((ext_vector_type(4)));

// async global->LDS, 16B per lane. HW semantics: LDS dest = wave-uniform base
// + lane*16. Our staging layout (half-offset 8*tid) is exactly that.
__device__ __forceinline__ void async16(const _Float16* g, _Float16* l) {
    __builtin_amdgcn_global_load_lds(
        (const __attribute__((address_space(1))) void*)g,
        (__attribute__((address_space(3))) void*)l, 16, 0, 0);
}

// ------------------------------------------------------------------
// Stage A: per-proposal AABB, volume, sem mask
// ------------------------------------------------------------------
__global__ void prep_prop(const float* __restrict__ logits,
                          const float* __restrict__ corners,
                          float* __restrict__ mn, float* __restrict__ mx,
                          float* __restrict__ vol, float* __restrict__ msk)
{
    int idx = blockIdx.x * 256 + threadIdx.x;      // 8192
    const float* c = corners + (size_t)idx * 24;
    float mn0 = c[0], mn1 = c[1], mn2 = c[2];
    float mx0 = mn0, mx1 = mn1, mx2 = mn2;
#pragma unroll
    for (int k = 1; k < 8; k++) {
        float v0 = c[k*3+0], v1 = c[k*3+1], v2 = c[k*3+2];
        mn0 = fminf(mn0, v0); mx0 = fmaxf(mx0, v0);
        mn1 = fminf(mn1, v1); mx1 = fmaxf(mx1, v1);
        mn2 = fminf(mn2, v2); mx2 = fmaxf(mx2, v2);
    }
    mn[idx*3+0] = mn0; mn[idx*3+1] = mn1; mn[idx*3+2] = mn2;
    mx[idx*3+0] = mx0; mx[idx*3+1] = mx1; mx[idx*3+2] = mx2;
    vol[idx] = (mx0-mn0)*(mx1-mn1)*(mx2-mn2);
    const float* lg = logits + (size_t)idx * 19;
    float bv = lg[0]; int bi = 0;
#pragma unroll
    for (int k = 1; k < 19; k++) { float v = lg[k]; if (v > bv) { bv = v; bi = k; } }
    msk[idx] = (bi != 18) ? 1.0f : 0.0f;
}

// ------------------------------------------------------------------
// Stage B: box query -> IoU argmax (first-max tiebreak)
// ------------------------------------------------------------------
__global__ void box_match(const float* __restrict__ box_query,
                          const float* __restrict__ mn_p, const float* __restrict__ mx_p,
                          const float* __restrict__ vol_p, const float* __restrict__ msk,
                          int* __restrict__ match_idx)
{
    int gq = blockIdx.x * 256 + threadIdx.x;   // 2048
    int b = gq >> 6;
    const float* cq = box_query + (size_t)gq * 24;
    float mn0 = cq[0], mn1 = cq[1], mn2 = cq[2];
    float mx0 = mn0, mx1 = mn1, mx2 = mn2;
#pragma unroll
    for (int k = 1; k < 8; k++) {
        float v0 = cq[k*3+0], v1 = cq[k*3+1], v2 = cq[k*3+2];
        mn0 = fminf(mn0, v0); mx0 = fmaxf(mx0, v0);
        mn1 = fminf(mn1, v1); mx1 = fmaxf(mx1, v1);
        mn2 = fminf(mn2, v2); mx2 = fmaxf(mx2, v2);
    }
    float volq = (mx0-mn0)*(mx1-mn1)*(mx2-mn2);
    const float* mnb = mn_p + (size_t)b * 768;
    const float* mxb = mx_p + (size_t)b * 768;
    const float* vb  = vol_p + (size_t)b * 256;
    const float* mb  = msk + (size_t)b * 256;
    float best = -1.0f; int bi = 0;
    for (int p = 0; p < 256; p++) {
        float e0 = fminf(mx0, mxb[p*3+0]) - fmaxf(mn0, mnb[p*3+0]); e0 = fmaxf(e0, 0.0f);
        float e1 = fminf(mx1, mxb[p*3+1]) - fmaxf(mn1, mnb[p*3+1]); e1 = fmaxf(e1, 0.0f);
        float e2 = fminf(mx2, mxb[p*3+2]) - fmaxf(mn2, mnb[p*3+2]); e2 = fmaxf(e2, 0.0f);
        float inter = (e0*e1)*e2;
        float iou = inter / (volq + vb[p] - inter + 1e-8f) * mb[p];
        if (iou > best) { best = iou; bi = p; }   // strict > keeps first
    }
    match_idx[gq] = bi;
}

// ------------------------------------------------------------------
// Stage C: click NN argmin (first-min tiebreak); one wave per click
// ------------------------------------------------------------------
__global__ void click_nn(const float* __restrict__ click_query,
                         const float* __restrict__ enc_xyz,
                         int* __restrict__ nn_ids)
{
    int gq = blockIdx.x * 4 + (threadIdx.x >> 6);   // 2048 waves
    int lane = threadIdx.x & 63;
    int b = gq >> 6;
    float cx = click_query[gq*3+0];
    float cy = click_query[gq*3+1];
    float cz = click_query[gq*3+2];
    const float* ex = enc_xyz + (size_t)b * 4096 * 3;
    float best = 3.4e38f; int bidx = 0;
    for (int p = lane; p < 4096; p += 64) {
        float dx = cx - ex[p*3+0];
        float dy = cy - ex[p*3+1];
        float dz = cz - ex[p*3+2];
        float d = dx*dx + dy*dy;
        d = d + dz*dz;
        if (d < best) { best = d; bidx = p; }
    }
#pragma unroll
    for (int off = 32; off; off >>= 1) {
        float ov = __shfl_down(best, off);
        int   oi = __shfl_down(bidx, off);
        if (ov < best || (ov == best && oi < bidx)) { best = ov; bidx = oi; }
    }
    if (lane == 0) nn_ids[gq] = bidx;
}

// ------------------------------------------------------------------
// Stage D+E fused: gather box/click feats + fourier pos embed
// block = one row (2048), 256 threads
// ------------------------------------------------------------------
__global__ void gather_pos(const float* __restrict__ prop_features,
                           const float* __restrict__ enc_features,
                           const int* __restrict__ match_idx,
                           const int* __restrict__ nn_ids,
                           const float* __restrict__ cq,
                           const float* __restrict__ pc_min,
                           const float* __restrict__ pc_max,
                           const float* __restrict__ gB,
                           _Float16* __restrict__ box_in,
                           _Float16* __restrict__ click_in)
{
    int row = blockIdx.x;     // 2048
    int c = threadIdx.x;      // 256
    int b = row >> 6;
    box_in[(size_t)row*256 + c] =
        (_Float16)prop_features[((size_t)b*256 + match_idx[row])*256 + c];
    click_in[(size_t)row*512 + c] =
        (_Float16)enc_features[((size_t)b*4096 + nn_ids[row])*256 + c];
    // pos embed: threads 0..127 -> sin, 128..255 -> cos (j = c & 127)
    int j = c & 127;
    float m0 = pc_min[b*3+0], m1 = pc_min[b*3+1], m2 = pc_min[b*3+2];
    float tx = (cq[row*3+0] - m0) / (pc_max[b*3+0] - m0) * TWO_PI;
    float ty = (cq[row*3+1] - m1) / (pc_max[b*3+1] - m1) * TWO_PI;
    float tz = (cq[row*3+2] - m2) / (pc_max[b*3+2] - m2) * TWO_PI;
    float p = tx * gB[j] + ty * gB[128+j] + tz * gB[256+j];
    float v = (c < 128) ? sinf(p) : cosf(p);
    click_in[(size_t)row*512 + 256 + c] = (_Float16)v;
}

// ------------------------------------------------------------------
// Transpose+convert core: src fp32 [K][N] -> dst f16 [N][K], 64x64 tile
// ------------------------------------------------------------------
__device__ __forceinline__ void transpose_core(
    const float* __restrict__ src, _Float16* __restrict__ dst,
    int K, int N, _Float16* t)
{
    int n0 = blockIdx.x * 64, k0 = blockIdx.y * 64;
    int tid = threadIdx.x;          // 256
    int r = tid >> 4;               // 0..15
    int c4 = (tid & 15) * 4;
#pragma unroll
    for (int p = 0; p < 4; p++) {
        int k = r + p*16;
        float4 v = *(const float4*)(src + (size_t)(k0+k)*N + n0 + c4);
        t[(c4+0)*68 + k] = (_Float16)v.x;
        t[(c4+1)*68 + k] = (_Float16)v.y;
        t[(c4+2)*68 + k] = (_Float16)v.z;
        t[(c4+3)*68 + k] = (_Float16)v.w;
    }
    __syncthreads();
    int ck = (tid & 15) * 4;        // k group of 4
#pragma unroll
    for (int p = 0; p < 4; p++) {
        int n = r + p*16;
        half4 v = *(const half4*)(t + n*68 + ck);
        *(half4*)(dst + (size_t)(n0+n)*K + k0 + ck) = v;
    }
}

// fused pair for the two w2 weights (same shape K=768,N=6144)
__global__ void transpose_w2(const float* __restrict__ s0, const float* __restrict__ s1,
                             _Float16* __restrict__ d0, _Float16* __restrict__ d1)
{
    __shared__ _Float16 t[64*68];
    if (blockIdx.z == 0) transpose_core(s0, d0, 768, 6144, t);
    else                 transpose_core(s1, d1, 768, 6144, t);
}

// fused pair for the two w1 weights (K=256 / K=512, N=768)
__global__ void transpose_w1(const float* __restrict__ s0, const float* __restrict__ s1,
                             _Float16* __restrict__ d0, _Float16* __restrict__ d1)
{
    __shared__ _Float16 t[64*68];
    if (blockIdx.z == 0) {
        if (blockIdx.y * 64 >= 256) return;
        transpose_core(s0, d0, 256, 768, t);
    } else {
        transpose_core(s1, d1, 512, 768, t);
    }
}

// ------------------------------------------------------------------
// f16 MFMA GEMM core: C[M,N] = A[M,K] @ Bt[N,K]^T + bias
// 128x128 tile, BK=32, 4 waves each 64x64 (4x4 of 16x16x32 mfma),
// global_load_lds width-16 staging.
// MODE 0: relu -> f16 Hout (row-major, stride N)
// MODE 1: fp32 -> Fout, prompt reshape: off=(m>>6)*786432+brOff+(m&63)*6144+n
// ------------------------------------------------------------------
template<int MODE>
__device__ __forceinline__ void gemm_core(
    const _Float16* __restrict__ A, const _Float16* __restrict__ Bt,
    const float* __restrict__ bias, int N, int K,
    _Float16* __restrict__ Hout, float* __restrict__ Fout, long brOff,
    _Float16* As, _Float16* Bs)
{
    const int tid = threadIdx.x;
    const int wave = tid >> 6, lane = tid & 63;
    const int bm = blockIdx.x, bn = blockIdx.y;
    const int waveM = (wave & 1) * 64, waveN = (wave >> 1) * 64;
    const int sr = tid >> 2;          // staging row 0..63
    const int sk = (tid & 3) * 8;     // staging k offset {0,8,16,24}
    const int nrow = lane & 15, kgrp = (lane >> 4) * 8;

    floatx4 acc[4][4];
#pragma unroll
    for (int i = 0; i < 4; i++)
#pragma unroll
        for (int j = 0; j < 4; j++) { floatx4 z = {0.f,0.f,0.f,0.f}; acc[i][j] = z; }

    const _Float16* Ar0 = A  + (size_t)(bm*128 + sr) * K + sk;
    const _Float16* Ar1 = Ar0 + (size_t)64 * K;
    const _Float16* Br0 = Bt + (size_t)(bn*128 + sr) * K + sk;
    const _Float16* Br1 = Br0 + (size_t)64 * K;
    // wave-uniform LDS bases; HW scatters lane i at base + i*16B
    _Float16* lA0 = As + wave*512;
    _Float16* lA1 = As + 2048 + wave*512;
    _Float16* lB0 = Bs + wave*512;
    _Float16* lB1 = Bs + 2048 + wave*512;

    for (int kk = 0; kk < K; kk += 32) {
        __syncthreads();                 // prior-tile LDS reads done
        async16(Ar0 + kk, lA0);
        async16(Ar1 + kk, lA1);
        async16(Br0 + kk, lB0);
        async16(Br1 + kk, lB1);
        __syncthreads();                 // staging complete (vmcnt drained)
        half8 af[4], bf[4];
#pragma unroll
        for (int i = 0; i < 4; i++)
            af[i] = *(const half8*)(As + (waveM + i*16 + nrow)*32 + kgrp);
#pragma unroll
        for (int j = 0; j < 4; j++)
            bf[j] = *(const half8*)(Bs + (waveN + j*16 + nrow)*32 + kgrp);
#pragma unroll
        for (int i = 0; i < 4; i++)
#pragma unroll
            for (int j = 0; j < 4; j++)
                acc[i][j] = __builtin_amdgcn_mfma_f32_16x16x32_f16(af[i], bf[j], acc[i][j], 0, 0, 0);
    }

    // epilogue: C/D layout col = lane&15, row = (lane>>4)*4 + reg
#pragma unroll
    for (int i = 0; i < 4; i++) {
#pragma unroll
        for (int j = 0; j < 4; j++) {
            int col = bn*128 + waveN + j*16 + nrow;
            float bv = bias[col];
#pragma unroll
            for (int r = 0; r < 4; r++) {
                int row = bm*128 + waveM + i*16 + (lane >> 4)*4 + r;
                float v = acc[i][j][r] + bv;
                if (MODE == 0) {
                    v = v > 0.f ? v : 0.f;
                    Hout[(size_t)row * N + col] = (_Float16)v;
                } else {
                    size_t off = (size_t)(row >> 6) * 786432 + (size_t)brOff
                               + (size_t)(row & 63) * 6144 + col;
                    Fout[off] = v;
                }
            }
        }
    }
}

// layer-1: both branches in one launch (z: 0=box K=256, 1=click K=512), N=768
__global__ __launch_bounds__(256) void gemm_l1(
    const _Float16* __restrict__ A0, const _Float16* __restrict__ A1,
    const _Float16* __restrict__ B0, const _Float16* __restrict__ B1,
    const float* __restrict__ b0, const float* __restrict__ b1,
    _Float16* __restrict__ H0, _Float16* __restrict__ H1)
{
    __shared__ _Float16 As[4096];
    __shared__ _Float16 Bs[4096];
    if (blockIdx.z == 0)
        gemm_core<0>(A0, B0, b0, 768, 256, H0, nullptr, 0, As, Bs);
    else
        gemm_core<0>(A1, B1, b1, 768, 512, H1, nullptr, 0, As, Bs);
}

// layer-2: both branches in one launch (z: 0=box, 1=click), N=6144, K=768
__global__ __launch_bounds__(256) void gemm_l2(
    const _Float16* __restrict__ A0, const _Float16* __restrict__ A1,
    const _Float16* __restrict__ B0, const _Float16* __restrict__ B1,
    const float* __restrict__ b0, const float* __restrict__ b1,
    float* __restrict__ out)
{
    __shared__ _Float16 As[4096];
    __shared__ _Float16 Bs[4096];
    if (blockIdx.z == 0)
        gemm_core<1>(A0, B0, b0, 6144, 768, nullptr, out, 0, As, Bs);
    else
        gemm_core<1>(A1, B1, b1, 6144, 768, nullptr, out, 393216, As, Bs);
}

// ------------------------------------------------------------------
// prompt_mask: repeat qmasks VQ=8, concat box|click
// ------------------------------------------------------------------
__global__ void write_mask(const float* __restrict__ box_qmask,
                           const float* __restrict__ click_qmask,
                           float* __restrict__ out)
{
    int idx = blockIdx.x * 256 + threadIdx.x;   // 32768
    int b = idx >> 10, i = idx & 1023;
    float v = (i < 512) ? box_qmask[b*64 + (i >> 3)]
                        : click_qmask[b*64 + ((i - 512) >> 3)];
    out[25165824 + idx] = v;
}

// ------------------------------------------------------------------
extern "C" void kernel_launch(void* const* d_in, const int* in_sizes, int n_in,
                              void* d_out, int out_size, void* d_ws, size_t ws_size,
                              hipStream_t stream)
{
    const float* sem   = (const float*)d_in[0];
    const float* propf = (const float*)d_in[1];
    const float* boxc  = (const float*)d_in[2];
    const float* encx  = (const float*)d_in[3];
    const float* encf  = (const float*)d_in[4];
    const float* pcmin = (const float*)d_in[5];
    const float* pcmax = (const float*)d_in[6];
    const float* boxq  = (const float*)d_in[7];
    const float* boxm  = (const float*)d_in[8];
    const float* clkq  = (const float*)d_in[9];
    const float* clkm  = (const float*)d_in[10];
    const float* gB    = (const float*)d_in[11];
    const float* bw1   = (const float*)d_in[12];
    const float* bb1   = (const float*)d_in[13];
    const float* bw2   = (const float*)d_in[14];
    const float* bb2   = (const float*)d_in[15];
    const float* cw1   = (const float*)d_in[16];
    const float* cb1   = (const float*)d_in[17];
    const float* cw2   = (const float*)d_in[18];
    const float* cb2   = (const float*)d_in[19];
    float* out = (float*)d_out;
    char* ws = (char*)d_ws;

    float* p_mn  = (float*)(ws + 0);
    float* p_mx  = (float*)(ws + 98304);
    float* p_vol = (float*)(ws + 196608);
    float* p_msk = (float*)(ws + 229376);
    int* midx    = (int*)(ws + 262144);
    int* nnids   = (int*)(ws + 270336);
    _Float16* box_in   = (_Float16*)(ws + 278528);    // 2048x256
    _Float16* click_in = (_Float16*)(ws + 1327104);   // 2048x512
    _Float16* h_box    = (_Float16*)(ws + 3424256);   // 2048x768
    _Float16* h_click  = (_Float16*)(ws + 6569984);   // 2048x768
    _Float16* w1t_box  = (_Float16*)(ws + 9715712);   // 768x256
    _Float16* w2t_box  = (_Float16*)(ws + 10108928);  // 6144x768
    _Float16* w1t_clk  = (_Float16*)(ws + 19546112);  // 768x512
    _Float16* w2t_clk  = (_Float16*)(ws + 20332544);  // 6144x768

    prep_prop<<<32, 256, 0, stream>>>(sem, boxc, p_mn, p_mx, p_vol, p_msk);
    box_match<<<8, 256, 0, stream>>>(boxq, p_mn, p_mx, p_vol, p_msk, midx);
    click_nn<<<512, 256, 0, stream>>>(clkq, encx, nnids);
    gather_pos<<<2048, 256, 0, stream>>>(propf, encf, midx, nnids,
                                         clkq, pcmin, pcmax, gB, box_in, click_in);

    transpose_w1<<<dim3(12, 8, 2),  256, 0, stream>>>(bw1, cw1, w1t_box, w1t_clk);
    transpose_w2<<<dim3(96, 12, 2), 256, 0, stream>>>(bw2, cw2, w2t_box, w2t_clk);

    gemm_l1<<<dim3(16, 6, 2),  256, 0, stream>>>(box_in, click_in, w1t_box, w1t_clk,
                                                 bb1, cb1, h_box, h_click);
    gemm_l2<<<dim3(16, 48, 2), 256, 0, stream>>>(h_box, h_click, w2t_box, w2t_clk,
                                                 bb2, cb2, out);

    write_mask<<<128, 256, 0, stream>>>(boxm, clkm, out);
}

// Round 3
// 372.150 us; speedup vs baseline: 1.1298x; 1.0518x over previous
//
#include <hip/hip_runtime.h>

#define TWO_PI 6.283185307179586f

typedef _Float16 half8 __attribute__((ext_vector_type(8)));
typedef _Float16 half4 __attribute__((ext_vector_type(4)));
typedef float floatx4 __attribute__((ext_vector_type(4)));

// async global->LDS, 16B per lane. LDS dest = wave-uniform base + lane*16.
__device__ __forceinline__ void async16(const _Float16* g, _Float16* l) {
    __builtin_amdgcn_global_load_lds(
        (const __attribute__((address_space(1))) void*)g,
        (__attribute__((address_space(3))) void*)l, 16, 0, 0);
}

// ------------------------------------------------------------------
// Fused: per-batch proposal AABB/vol/semmask (256 thr) -> LDS ->
//        box-query IoU argmax (threads 0..63). One block per batch.
// ------------------------------------------------------------------
__global__ void prep_box(const float* __restrict__ logits,
                         const float* __restrict__ corners,
                         const float* __restrict__ box_query,
                         int* __restrict__ match_idx)
{
    __shared__ float smn[256][3], smx[256][3], svol[256], smsk[256];
    int b = blockIdx.x, t = threadIdx.x;
    {
        const float* c = corners + ((size_t)b*256 + t) * 24;
        float mn0 = c[0], mn1 = c[1], mn2 = c[2];
        float mx0 = mn0, mx1 = mn1, mx2 = mn2;
#pragma unroll
        for (int k = 1; k < 8; k++) {
            float v0 = c[k*3+0], v1 = c[k*3+1], v2 = c[k*3+2];
            mn0 = fminf(mn0, v0); mx0 = fmaxf(mx0, v0);
            mn1 = fminf(mn1, v1); mx1 = fmaxf(mx1, v1);
            mn2 = fminf(mn2, v2); mx2 = fmaxf(mx2, v2);
        }
        smn[t][0] = mn0; smn[t][1] = mn1; smn[t][2] = mn2;
        smx[t][0] = mx0; smx[t][1] = mx1; smx[t][2] = mx2;
        svol[t] = (mx0-mn0)*(mx1-mn1)*(mx2-mn2);
        const float* lg = logits + ((size_t)b*256 + t) * 19;
        float bv = lg[0]; int bi = 0;
#pragma unroll
        for (int k = 1; k < 19; k++) { float v = lg[k]; if (v > bv) { bv = v; bi = k; } }
        smsk[t] = (bi != 18) ? 1.0f : 0.0f;
    }
    __syncthreads();
    if (t < 64) {
        int gq = b*64 + t;
        const float* cq = box_query + (size_t)gq * 24;
        float mn0 = cq[0], mn1 = cq[1], mn2 = cq[2];
        float mx0 = mn0, mx1 = mn1, mx2 = mn2;
#pragma unroll
        for (int k = 1; k < 8; k++) {
            float v0 = cq[k*3+0], v1 = cq[k*3+1], v2 = cq[k*3+2];
            mn0 = fminf(mn0, v0); mx0 = fmaxf(mx0, v0);
            mn1 = fminf(mn1, v1); mx1 = fmaxf(mx1, v1);
            mn2 = fminf(mn2, v2); mx2 = fmaxf(mx2, v2);
        }
        float volq = (mx0-mn0)*(mx1-mn1)*(mx2-mn2);
        float best = -1.0f; int bi = 0;
        for (int p = 0; p < 256; p++) {
            float e0 = fminf(mx0, smx[p][0]) - fmaxf(mn0, smn[p][0]); e0 = fmaxf(e0, 0.0f);
            float e1 = fminf(mx1, smx[p][1]) - fmaxf(mn1, smn[p][1]); e1 = fmaxf(e1, 0.0f);
            float e2 = fminf(mx2, smx[p][2]) - fmaxf(mn2, smn[p][2]); e2 = fmaxf(e2, 0.0f);
            float inter = (e0*e1)*e2;
            float iou = inter / (volq + svol[p] - inter + 1e-8f) * smsk[p];
            if (iou > best) { best = iou; bi = p; }   // strict > keeps first
        }
        match_idx[gq] = bi;
    }
}

// ------------------------------------------------------------------
// click NN argmin (first-min tiebreak); one wave per click
// ------------------------------------------------------------------
__global__ void click_nn(const float* __restrict__ click_query,
                         const float* __restrict__ enc_xyz,
                         int* __restrict__ nn_ids)
{
    int gq = blockIdx.x * 4 + (threadIdx.x >> 6);   // 2048 waves
    int lane = threadIdx.x & 63;
    int b = gq >> 6;
    float cx = click_query[gq*3+0];
    float cy = click_query[gq*3+1];
    float cz = click_query[gq*3+2];
    const float* ex = enc_xyz + (size_t)b * 4096 * 3;
    float best = 3.4e38f; int bidx = 0;
    for (int p = lane; p < 4096; p += 64) {
        float dx = cx - ex[p*3+0];
        float dy = cy - ex[p*3+1];
        float dz = cz - ex[p*3+2];
        float d = dx*dx + dy*dy;
        d = d + dz*dz;
        if (d < best) { best = d; bidx = p; }
    }
#pragma unroll
    for (int off = 32; off; off >>= 1) {
        float ov = __shfl_down(best, off);
        int   oi = __shfl_down(bidx, off);
        if (ov < best || (ov == best && oi < bidx)) { best = ov; bidx = oi; }
    }
    if (lane == 0) nn_ids[gq] = bidx;
}

// ------------------------------------------------------------------
// Fused: gather box/click feats + fourier pos embed + prompt mask
// ------------------------------------------------------------------
__global__ void gather_pos(const float* __restrict__ prop_features,
                           const float* __restrict__ enc_features,
                           const int* __restrict__ match_idx,
                           const int* __restrict__ nn_ids,
                           const float* __restrict__ cq,
                           const float* __restrict__ pc_min,
                           const float* __restrict__ pc_max,
                           const float* __restrict__ gB,
                           const float* __restrict__ box_qmask,
                           const float* __restrict__ click_qmask,
                           _Float16* __restrict__ box_in,
                           _Float16* __restrict__ click_in,
                           float* __restrict__ out)
{
    int row = blockIdx.x;     // 2048
    int c = threadIdx.x;      // 256
    int b = row >> 6;
    box_in[(size_t)row*256 + c] =
        (_Float16)prop_features[((size_t)b*256 + match_idx[row])*256 + c];
    click_in[(size_t)row*512 + c] =
        (_Float16)enc_features[((size_t)b*4096 + nn_ids[row])*256 + c];
    int j = c & 127;
    float m0 = pc_min[b*3+0], m1 = pc_min[b*3+1], m2 = pc_min[b*3+2];
    float tx = (cq[row*3+0] - m0) / (pc_max[b*3+0] - m0) * TWO_PI;
    float ty = (cq[row*3+1] - m1) / (pc_max[b*3+1] - m1) * TWO_PI;
    float tz = (cq[row*3+2] - m2) / (pc_max[b*3+2] - m2) * TWO_PI;
    float p = tx * gB[j] + ty * gB[128+j] + tz * gB[256+j];
    float v = (c < 128) ? sinf(p) : cosf(p);
    click_in[(size_t)row*512 + 256 + c] = (_Float16)v;
    // prompt mask: 16 elements per row-block
    if (c < 16) {
        int idx = row*16 + c;            // 0..32767
        int mb = idx >> 10, i = idx & 1023;
        float mv = (i < 512) ? box_qmask[mb*64 + (i >> 3)]
                             : click_qmask[mb*64 + ((i - 512) >> 3)];
        out[25165824 + idx] = mv;
    }
}

// ------------------------------------------------------------------
// Transpose+convert: src fp32 [K][N] -> dst f16 [N][K], 64x64 tile
// ------------------------------------------------------------------
__device__ __forceinline__ void transpose_core(
    const float* __restrict__ src, _Float16* __restrict__ dst,
    int K, int N, _Float16* t)
{
    int n0 = blockIdx.x * 64, k0 = blockIdx.y * 64;
    int tid = threadIdx.x;          // 256
    int r = tid >> 4;               // 0..15
    int c4 = (tid & 15) * 4;
#pragma unroll
    for (int p = 0; p < 4; p++) {
        int k = r + p*16;
        float4 v = *(const float4*)(src + (size_t)(k0+k)*N + n0 + c4);
        t[(c4+0)*68 + k] = (_Float16)v.x;
        t[(c4+1)*68 + k] = (_Float16)v.y;
        t[(c4+2)*68 + k] = (_Float16)v.z;
        t[(c4+3)*68 + k] = (_Float16)v.w;
    }
    __syncthreads();
    int ck = (tid & 15) * 4;
#pragma unroll
    for (int p = 0; p < 4; p++) {
        int n = r + p*16;
        half4 v = *(const half4*)(t + n*68 + ck);
        *(half4*)(dst + (size_t)(n0+n)*K + k0 + ck) = v;
    }
}

__global__ void transpose_w2(const float* __restrict__ s0, const float* __restrict__ s1,
                             _Float16* __restrict__ d0, _Float16* __restrict__ d1)
{
    __shared__ _Float16 t[64*68];
    if (blockIdx.z == 0) transpose_core(s0, d0, 768, 6144, t);
    else                 transpose_core(s1, d1, 768, 6144, t);
}

__global__ void transpose_w1(const float* __restrict__ s0, const float* __restrict__ s1,
                             _Float16* __restrict__ d0, _Float16* __restrict__ d1)
{
    __shared__ _Float16 t[64*68];
    if (blockIdx.z == 0) {
        if (blockIdx.y * 64 >= 256) return;
        transpose_core(s0, d0, 256, 768, t);
    } else {
        transpose_core(s1, d1, 512, 768, t);
    }
}

// ------------------------------------------------------------------
// f16 MFMA GEMM core: C[M,N] = A[M,K] @ Bt[N,K]^T + bias
// 128x128 tile, BK=64, XOR-swizzled LDS (conflict-free ds_read_b128),
// global_load_lds width-16 staging. K % 64 == 0.
// LDS layout: slot (row, jslot 0..7 of 8 halves) holds data k-block
//             jdata = jslot ^ (row & 7). Row stride = 64 halves.
// MODE 0: relu -> f16 Hout (row-major, stride N)
// MODE 1: fp32 -> Fout, prompt reshape: off=(m>>6)*786432+brOff+(m&63)*6144+n
// ------------------------------------------------------------------
template<int MODE>
__device__ __forceinline__ void gemm_core(
    const _Float16* __restrict__ A, const _Float16* __restrict__ Bt,
    const float* __restrict__ bias, int N, int K,
    _Float16* __restrict__ Hout, float* __restrict__ Fout, long brOff,
    _Float16* As, _Float16* Bs)
{
    const int tid = threadIdx.x;
    const int wave = tid >> 6, lane = tid & 63;
    const int bm = blockIdx.x, bn = blockIdx.y;
    const int waveM = (wave & 1) * 64, waveN = (wave >> 1) * 64;
    const int nrow = lane & 15;         // fragment row within 16
    const int kq   = lane >> 4;         // fragment k quarter (0..3)

    // staging: thread -> (row = q*32 + (tid>>3), jslot = tid&7),
    // fetches global data k-block jdata = jslot ^ (row&7)
    const int srow = tid >> 3;                                  // 0..31
    const int jdat = ((tid & 7) ^ (srow & 7)) * 8;              // half offset

    floatx4 acc[4][4];
#pragma unroll
    for (int i = 0; i < 4; i++)
#pragma unroll
        for (int j = 0; j < 4; j++) { floatx4 z = {0.f,0.f,0.f,0.f}; acc[i][j] = z; }

    const _Float16* Ab[4]; const _Float16* Bb[4];
    _Float16 *lA[4], *lB[4];
#pragma unroll
    for (int q = 0; q < 4; q++) {
        Ab[q] = A  + (size_t)(bm*128 + q*32 + srow) * K + jdat;
        Bb[q] = Bt + (size_t)(bn*128 + q*32 + srow) * K + jdat;
        lA[q] = As + q*2048 + wave*512;
        lB[q] = Bs + q*2048 + wave*512;
    }

    for (int kk = 0; kk < K; kk += 64) {
        __syncthreads();                 // prior-tile LDS reads done
#pragma unroll
        for (int q = 0; q < 4; q++) async16(Ab[q] + kk, lA[q]);
#pragma unroll
        for (int q = 0; q < 4; q++) async16(Bb[q] + kk, lB[q]);
        __syncthreads();                 // staging complete
#pragma unroll
        for (int h = 0; h < 2; h++) {
            const int sw = (((kq + h*4) ^ (nrow & 7)) * 8);
            half8 af[4], bf[4];
#pragma unroll
            for (int i = 0; i < 4; i++)
                af[i] = *(const half8*)(As + (waveM + i*16 + nrow)*64 + sw);
#pragma unroll
            for (int j = 0; j < 4; j++)
                bf[j] = *(const half8*)(Bs + (waveN + j*16 + nrow)*64 + sw);
#pragma unroll
            for (int i = 0; i < 4; i++)
#pragma unroll
                for (int j = 0; j < 4; j++)
                    acc[i][j] = __builtin_amdgcn_mfma_f32_16x16x32_f16(af[i], bf[j], acc[i][j], 0, 0, 0);
        }
    }

    // epilogue: C/D layout col = lane&15, row = (lane>>4)*4 + reg
#pragma unroll
    for (int i = 0; i < 4; i++) {
#pragma unroll
        for (int j = 0; j < 4; j++) {
            int col = bn*128 + waveN + j*16 + nrow;
            float bv = bias[col];
#pragma unroll
            for (int r = 0; r < 4; r++) {
                int row = bm*128 + waveM + i*16 + kq*4 + r;
                float v = acc[i][j][r] + bv;
                if (MODE == 0) {
                    v = v > 0.f ? v : 0.f;
                    Hout[(size_t)row * N + col] = (_Float16)v;
                } else {
                    size_t off = (size_t)(row >> 6) * 786432 + (size_t)brOff
                               + (size_t)(row & 63) * 6144 + col;
                    Fout[off] = v;
                }
            }
        }
    }
}

// layer-1: both branches (z: 0=box K=256, 1=click K=512), N=768
__global__ __launch_bounds__(256) void gemm_l1(
    const _Float16* __restrict__ A0, const _Float16* __restrict__ A1,
    const _Float16* __restrict__ B0, const _Float16* __restrict__ B1,
    const float* __restrict__ b0, const float* __restrict__ b1,
    _Float16* __restrict__ H0, _Float16* __restrict__ H1)
{
    __shared__ _Float16 As[8192];
    __shared__ _Float16 Bs[8192];
    if (blockIdx.z == 0)
        gemm_core<0>(A0, B0, b0, 768, 256, H0, nullptr, 0, As, Bs);
    else
        gemm_core<0>(A1, B1, b1, 768, 512, H1, nullptr, 0, As, Bs);
}

// layer-2: both branches (z: 0=box, 1=click), N=6144, K=768
__global__ __launch_bounds__(256) void gemm_l2(
    const _Float16* __restrict__ A0, const _Float16* __restrict__ A1,
    const _Float16* __restrict__ B0, const _Float16* __restrict__ B1,
    const float* __restrict__ b0, const float* __restrict__ b1,
    float* __restrict__ out)
{
    __shared__ _Float16 As[8192];
    __shared__ _Float16 Bs[8192];
    if (blockIdx.z == 0)
        gemm_core<1>(A0, B0, b0, 6144, 768, nullptr, out, 0, As, Bs);
    else
        gemm_core<1>(A1, B1, b1, 6144, 768, nullptr, out, 393216, As, Bs);
}

// ------------------------------------------------------------------
extern "C" void kernel_launch(void* const* d_in, const int* in_sizes, int n_in,
                              void* d_out, int out_size, void* d_ws, size_t ws_size,
                              hipStream_t stream)
{
    const float* sem   = (const float*)d_in[0];
    const float* propf = (const float*)d_in[1];
    const float* boxc  = (const float*)d_in[2];
    const float* encx  = (const float*)d_in[3];
    const float* encf  = (const float*)d_in[4];
    const float* pcmin = (const float*)d_in[5];
    const float* pcmax = (const float*)d_in[6];
    const float* boxq  = (const float*)d_in[7];
    const float* boxm  = (const float*)d_in[8];
    const float* clkq  = (const float*)d_in[9];
    const float* clkm  = (const float*)d_in[10];
    const float* gB    = (const float*)d_in[11];
    const float* bw1   = (const float*)d_in[12];
    const float* bb1   = (const float*)d_in[13];
    const float* bw2   = (const float*)d_in[14];
    const float* bb2   = (const float*)d_in[15];
    const float* cw1   = (const float*)d_in[16];
    const float* cb1   = (const float*)d_in[17];
    const float* cw2   = (const float*)d_in[18];
    const float* cb2   = (const float*)d_in[19];
    float* out = (float*)d_out;
    char* ws = (char*)d_ws;

    int* midx    = (int*)(ws + 262144);
    int* nnids   = (int*)(ws + 270336);
    _Float16* box_in   = (_Float16*)(ws + 278528);    // 2048x256
    _Float16* click_in = (_Float16*)(ws + 1327104);   // 2048x512
    _Float16* h_box    = (_Float16*)(ws + 3424256);   // 2048x768
    _Float16* h_click  = (_Float16*)(ws + 6569984);   // 2048x768
    _Float16* w1t_box  = (_Float16*)(ws + 9715712);   // 768x256
    _Float16* w2t_box  = (_Float16*)(ws + 10108928);  // 6144x768
    _Float16* w1t_clk  = (_Float16*)(ws + 19546112);  // 768x512
    _Float16* w2t_clk  = (_Float16*)(ws + 20332544);  // 6144x768

    prep_box<<<32, 256, 0, stream>>>(sem, boxc, boxq, midx);
    click_nn<<<512, 256, 0, stream>>>(clkq, encx, nnids);
    gather_pos<<<2048, 256, 0, stream>>>(propf, encf, midx, nnids,
                                         clkq, pcmin, pcmax, gB,
                                         boxm, clkm, box_in, click_in, out);

    transpose_w1<<<dim3(12, 8, 2),  256, 0, stream>>>(bw1, cw1, w1t_box, w1t_clk);
    transpose_w2<<<dim3(96, 12, 2), 256, 0, stream>>>(bw2, cw2, w2t_box, w2t_clk);

    gemm_l1<<<dim3(16, 6, 2),  256, 0, stream>>>(box_in, click_in, w1t_box, w1t_clk,
                                                 bb1, cb1, h_box, h_click);
    gemm_l2<<<dim3(16, 48, 2), 256, 0, stream>>>(h_box, h_click, w2t_box, w2t_clk,
                                                 bb2, cb2, out);
}